// Round 1
// baseline (432.939 us; speedup 1.0000x reference)
//
#include <hip/hip_runtime.h>

typedef __attribute__((ext_vector_type(4))) float f32x4;
typedef __attribute__((ext_vector_type(8))) short s16x8;
typedef __attribute__((ext_vector_type(4))) unsigned short u16x4;

#define B_    8
#define L_    512
#define LC_   2048
#define EMBD  1024

__device__ __forceinline__ float b2f(unsigned short u) {
  unsigned int i = ((unsigned int)u) << 16;
  float f; __builtin_memcpy(&f, &i, 4); return f;
}
__device__ __forceinline__ unsigned short f2b(float f) {
  unsigned int i; __builtin_memcpy(&i, &f, 4);
  unsigned int r = i + 0x7FFFu + ((i >> 16) & 1u);
  return (unsigned short)(r >> 16);
}

// async global->LDS, 16B per lane; LDS dest must be linear (base + lane*16)
#define GLL16(g, l)                                                         \
  __builtin_amdgcn_global_load_lds(                                         \
      (__attribute__((address_space(1))) void*)(g),                         \
      (__attribute__((address_space(3))) void*)(l), 16, 0, 0)

// ---------------------------------------------------------------- converts
__global__ __launch_bounds__(256) void convert_f32_bf16(
    const float* __restrict__ in, unsigned short* __restrict__ out, int n4) {
  int i = blockIdx.x * 256 + threadIdx.x;
  if (i >= n4) return;
  float4 v = ((const float4*)in)[i];
  u16x4 o = { f2b(v.x), f2b(v.y), f2b(v.z), f2b(v.w) };
  ((u16x4*)out)[i] = o;
}

// ---------------------------------------------------------------- rmsnorm
__global__ __launch_bounds__(256) void rmsnorm_kernel(
    const float* __restrict__ x, const float* __restrict__ w,
    unsigned short* __restrict__ out) {
  int row = blockIdx.x;            // 4096 rows of 1024
  int tid = threadIdx.x;
  float4 v = ((const float4*)(x + (size_t)row * EMBD))[tid];
  float ss = v.x*v.x + v.y*v.y + v.z*v.z + v.w*v.w;
#pragma unroll
  for (int o = 1; o < 64; o <<= 1) ss += __shfl_xor(ss, o);
  __shared__ float red[4];
  if ((tid & 63) == 0) red[tid >> 6] = ss;
  __syncthreads();
  float tot = red[0] + red[1] + red[2] + red[3];
  float rs = rsqrtf(tot * (1.0f / EMBD) + 1.1920928955078125e-07f);
  float4 wv = ((const float4*)w)[tid];
  u16x4 o = { f2b(v.x*rs*wv.x), f2b(v.y*rs*wv.y), f2b(v.z*rs*wv.z), f2b(v.w*rs*wv.w) };
  ((u16x4*)(out + (size_t)row * EMBD))[tid] = o;
}

// ---------------------------------------------------------------- rope (in-place on [4096][2048] bf16)
__global__ __launch_bounds__(256) void rope_kernel(unsigned short* __restrict__ q) {
  int idx = blockIdx.x * 256 + threadIdx.x;   // 4096*8*128
  int i   = idx & 127;
  int h   = (idx >> 7) & 7;
  int row = idx >> 10;
  int l   = row & (L_ - 1);
  size_t base = (size_t)row * 2048 + h * 256 + i;
  float x1 = b2f(q[base]);
  float x2 = b2f(q[base + 128]);
  float ts  = powf(10000.0f, (float)i * (2.0f / 256.0f));
  float rad = (float)l / ts;
  float s, c;
  sincosf(rad, &s, &c);
  q[base]       = f2b(x1 * c - x2 * s);
  q[base + 128] = f2b(x2 * c + x1 * s);
}

// ---------------------------------------------------------------- silu(g)*u
__global__ __launch_bounds__(256) void act_kernel(
    const unsigned short* __restrict__ g, const unsigned short* __restrict__ u,
    unsigned short* __restrict__ out, int n8) {
  int i = blockIdx.x * 256 + threadIdx.x;
  if (i >= n8) return;
  s16x8 gv = ((const s16x8*)g)[i];
  s16x8 uv = ((const s16x8*)u)[i];
  s16x8 ov;
#pragma unroll
  for (int j = 0; j < 8; ++j) {
    float gf = b2f((unsigned short)gv[j]);
    float uf = b2f((unsigned short)uv[j]);
    float s  = gf / (1.0f + __expf(-gf));
    ov[j] = (short)f2b(s * uf);
  }
  ((s16x8*)out)[i] = ov;
}

// ---------------------------------------------------------------- NT GEMM
// C[m][n] = sum_k A[m][k] * Bw[n][k]  (+ Res), A/Bw bf16 row-major.
// 128x128 tile, BK=64, 4 waves, 16x16x32 MFMA, global_load_lds staging with
// XOR swizzle (byte ^= (row&7)<<4 within 128B row) pre-applied on the global
// source so ds_read_b128 fragments are ~conflict-free.
template <int ADD_RES, int OUT_BF16>
__global__ __launch_bounds__(256, 2) void gemm_nt(
    const unsigned short* __restrict__ A, const unsigned short* __restrict__ Bw,
    const float* __restrict__ Res, void* __restrict__ C, int M, int N, int K) {
  __shared__ unsigned short As[128 * 64];
  __shared__ unsigned short Bs[128 * 64];
  const int tid = threadIdx.x;
  const int lane = tid & 63, wid = tid >> 6;
  const int l15 = lane & 15, l4 = lane >> 4;
  const int wr = wid >> 1, wc = wid & 1;
  const int m0 = blockIdx.y * 128, n0 = blockIdx.x * 128;

  const f32x4 fz = {0.f, 0.f, 0.f, 0.f};
  f32x4 acc[4][4];
#pragma unroll
  for (int i = 0; i < 4; ++i)
#pragma unroll
    for (int j = 0; j < 4; ++j) acc[i][j] = fz;

  for (int k0 = 0; k0 < K; k0 += 64) {
    __syncthreads();
#pragma unroll
    for (int i = 0; i < 4; ++i) {
      int Li = i * 4096 + tid * 16;
      int row = Li >> 7;
      int kb = (Li & 127) ^ ((row & 7) << 4);
      GLL16((const char*)(A + (size_t)(m0 + row) * K + k0) + kb, (char*)As + Li);
      GLL16((const char*)(Bw + (size_t)(n0 + row) * K + k0) + kb, (char*)Bs + Li);
    }
    __syncthreads();   // drains vmcnt before barrier -> staged data visible
#pragma unroll
    for (int kk = 0; kk < 2; ++kk) {
      s16x8 af[4], bfr[4];
#pragma unroll
      for (int mi = 0; mi < 4; ++mi) {
        int row = wr * 64 + mi * 16 + l15;
        int kb = (kk * 64 + l4 * 16) ^ ((row & 7) << 4);
        af[mi] = *(const s16x8*)((const char*)As + row * 128 + kb);
      }
#pragma unroll
      for (int ni = 0; ni < 4; ++ni) {
        int row = wc * 64 + ni * 16 + l15;
        int kb = (kk * 64 + l4 * 16) ^ ((row & 7) << 4);
        bfr[ni] = *(const s16x8*)((const char*)Bs + row * 128 + kb);
      }
#pragma unroll
      for (int mi = 0; mi < 4; ++mi)
#pragma unroll
        for (int ni = 0; ni < 4; ++ni)
          acc[mi][ni] = __builtin_amdgcn_mfma_f32_16x16x32_bf16(
              af[mi], bfr[ni], acc[mi][ni], 0, 0, 0);
    }
  }
#pragma unroll
  for (int mi = 0; mi < 4; ++mi) {
#pragma unroll
    for (int r = 0; r < 4; ++r) {
      int grow = m0 + wr * 64 + mi * 16 + l4 * 4 + r;
      size_t base = (size_t)grow * N + n0 + wc * 64 + l15;
#pragma unroll
      for (int ni = 0; ni < 4; ++ni) {
        float v = acc[mi][ni][r];
        size_t idx = base + ni * 16;
        if (ADD_RES) v += Res[idx];
        if (OUT_BF16) ((unsigned short*)C)[idx] = f2b(v);
        else          ((float*)C)[idx] = v;
      }
    }
  }
}

// ---------------------------------------------------------------- fused attention
// grid (qt=4, h=8, b=8), 512 threads (8 waves x 16 q-rows), KV tile 64.
// S^T = mfma(K, Q^T): rows=kv, cols=q -> per-lane online softmax (q = lane&15),
// cross-group reduce via shfl_xor(16/32). P redistributed to A-frag layout via
// packed-bf16 shuffles; PV uses V transposed in LDS (bank-spread swizzle).
#define SWZV(d) (((((d) & 7) ^ (((d) >> 3) & 7))) << 4)

__global__ __launch_bounds__(512, 2) void attn_kernel(
    const unsigned short* __restrict__ Q,   // [4096][2048] (roped)
    const unsigned short* __restrict__ Kc,  // [B][2048][256]
    const unsigned short* __restrict__ Vc,  // [B][2048][256]
    unsigned short* __restrict__ Ctx) {     // [4096][2048]
  __shared__ unsigned short Ks[64 * 256];   // 32KB, row stride 512B, swizzled
  __shared__ unsigned short Vt[256 * 64];   // 32KB, [d][kv], swizzled
  const int tid = threadIdx.x;
  const int lane = tid & 63, wid = tid >> 6;
  const int l15 = lane & 15, g = lane >> 4;
  const int qt = blockIdx.x, h = blockIdx.y, b = blockIdx.z;

  const size_t qrow = (size_t)(b * L_ + qt * 128 + wid * 16 + l15);
  const unsigned short* qp = Q + qrow * 2048 + h * 256;
  s16x8 qf[8];
#pragma unroll
  for (int kc = 0; kc < 8; ++kc) qf[kc] = *(const s16x8*)(qp + kc * 32 + g * 8);

  const f32x4 fz = {0.f, 0.f, 0.f, 0.f};
  f32x4 oacc[16];
#pragma unroll
  for (int i = 0; i < 16; ++i) oacc[i] = fz;
  float m_run = -__builtin_inff(), l_run = 0.f;

  const unsigned short* Kb = Kc + (size_t)b * LC_ * 256;
  const unsigned short* Vb = Vc + (size_t)b * LC_ * 256;

  for (int kt = 0; kt < LC_ / 64; ++kt) {
    __syncthreads();
    // stage K tile (64x256) via global_load_lds, source pre-swizzled
#pragma unroll
    for (int i = 0; i < 4; ++i) {
      int Li = i * 8192 + tid * 16;
      int row = Li >> 9;
      int kb = (Li & 511) ^ ((row & 7) << 4);
      GLL16((const char*)(Kb + (size_t)(kt * 64 + row) * 256) + kb, (char*)Ks + Li);
    }
    // stage V transposed: Vt[d][kv], pair-packed b32 writes
#pragma unroll
    for (int p = 0; p < 2; ++p) {
      int id = p * 512 + tid;
      int dgrp = id & 31;            // d0/8 (coalesced global reads)
      int kvp = id >> 5;             // 0..31
      int d0 = dgrp * 8, kv0 = kvp * 2;
      const unsigned short* v0p = Vb + (size_t)(kt * 64 + kv0) * 256 + d0;
      s16x8 r0 = *(const s16x8*)v0p;
      s16x8 r1 = *(const s16x8*)(v0p + 256);
#pragma unroll
      for (int j = 0; j < 8; ++j) {
        int d = d0 + j;
        unsigned int val = (unsigned int)(unsigned short)r0[j] |
                           ((unsigned int)(unsigned short)r1[j] << 16);
        *(unsigned int*)((char*)Vt + d * 128 + ((kv0 * 2) ^ SWZV(d))) = val;
      }
    }
    __syncthreads();

    // S^T = K * Q^T  (rows = kv, cols = q)
    f32x4 sacc[4];
#pragma unroll
    for (int mi = 0; mi < 4; ++mi) sacc[mi] = fz;
#pragma unroll
    for (int mi = 0; mi < 4; ++mi) {
      int row = mi * 16 + l15;
      int swz = (row & 7) << 4;
#pragma unroll
      for (int kc = 0; kc < 8; ++kc) {
        s16x8 kf = *(const s16x8*)((const char*)Ks + row * 512 + ((kc * 64 + g * 16) ^ swz));
        sacc[mi] = __builtin_amdgcn_mfma_f32_16x16x32_bf16(kf, qf[kc], sacc[mi], 0, 0, 0);
      }
    }
    // online softmax, per q-column (q = l15); kv per lane = mi*16 + g*4 + r
    float sv[4][4];
    float mt = -__builtin_inff();
#pragma unroll
    for (int mi = 0; mi < 4; ++mi)
#pragma unroll
      for (int r = 0; r < 4; ++r) {
        float t = sacc[mi][r] * 0.0625f;
        sv[mi][r] = t;
        mt = fmaxf(mt, t);
      }
    mt = fmaxf(mt, __shfl_xor(mt, 16));
    mt = fmaxf(mt, __shfl_xor(mt, 32));
    float mnew = fmaxf(m_run, mt);
    float alpha = __expf(m_run - mnew);
    float rs = 0.f;
#pragma unroll
    for (int mi = 0; mi < 4; ++mi)
#pragma unroll
      for (int r = 0; r < 4; ++r) {
        float p = __expf(sv[mi][r] - mnew);
        sv[mi][r] = p;
        rs += p;
      }
    rs += __shfl_xor(rs, 16);
    rs += __shfl_xor(rs, 32);
    l_run = l_run * alpha + rs;
    m_run = mnew;
    // rescale O (O rows are q' = g*4+r; alpha lives in lane q')
    float af4[4];
#pragma unroll
    for (int r = 0; r < 4; ++r) af4[r] = __shfl(alpha, g * 4 + r);
#pragma unroll
    for (int nd = 0; nd < 16; ++nd)
#pragma unroll
      for (int r = 0; r < 4; ++r) oacc[nd][r] *= af4[r];
    // pack P pairs to bf16 and redistribute into A-frag layout
    unsigned int pk[4][2];
#pragma unroll
    for (int ni = 0; ni < 4; ++ni) {
      pk[ni][0] = (unsigned int)f2b(sv[ni][0]) | ((unsigned int)f2b(sv[ni][1]) << 16);
      pk[ni][1] = (unsigned int)f2b(sv[ni][2]) | ((unsigned int)f2b(sv[ni][3]) << 16);
    }
    int cbase = (g & 1) << 3;
#pragma unroll
    for (int t = 0; t < 2; ++t) {
      unsigned int w[4];
#pragma unroll
      for (int jj = 0; jj < 4; ++jj) {
        int c = cbase + (jj << 1);
        int src = ((c >> 2) << 4) + l15;
        unsigned int ra = __shfl(pk[2 * t][jj & 1], src);
        unsigned int rb = __shfl(pk[2 * t + 1][jj & 1], src);
        w[jj] = (g < 2) ? ra : rb;
      }
      union { unsigned int u[4]; s16x8 v; } cvt;
      cvt.u[0] = w[0]; cvt.u[1] = w[1]; cvt.u[2] = w[2]; cvt.u[3] = w[3];
      s16x8 ap = cvt.v;
#pragma unroll
      for (int nd = 0; nd < 16; ++nd) {
        int d = nd * 16 + l15;
        s16x8 vf = *(const s16x8*)((const char*)Vt + d * 128 + ((t * 64 + g * 16) ^ SWZV(d)));
        oacc[nd] = __builtin_amdgcn_mfma_f32_16x16x32_bf16(ap, vf, oacc[nd], 0, 0, 0);
      }
    }
  }
  // finalize: divide by row sum, store bf16 ctx[b][l][h*256+d]
  float lf[4];
#pragma unroll
  for (int r = 0; r < 4; ++r) lf[r] = 1.0f / __shfl(l_run, g * 4 + r);
  const size_t orow0 = (size_t)(b * L_ + qt * 128 + wid * 16);
#pragma unroll
  for (int r = 0; r < 4; ++r) {
    size_t base = (orow0 + g * 4 + r) * 2048 + h * 256 + l15;
#pragma unroll
    for (int nd = 0; nd < 16; ++nd)
      Ctx[base + nd * 16] = f2b(oacc[nd][r] * lf[r]);
  }
}

// ---------------------------------------------------------------- launch
extern "C" void kernel_launch(void* const* d_in, const int* in_sizes, int n_in,
                              void* d_out, int out_size, void* d_ws, size_t ws_size,
                              hipStream_t stream) {
  const float* x   = (const float*)d_in[0];
  const float* tk  = (const float*)d_in[1];
  const float* tv  = (const float*)d_in[2];
  const float* ln1 = (const float*)d_in[3];
  const float* ln2 = (const float*)d_in[4];
  const float* Wq  = (const float*)d_in[5];
  const float* Wk  = (const float*)d_in[6];
  const float* Wv  = (const float*)d_in[7];
  const float* Wo  = (const float*)d_in[8];
  const float* Wg  = (const float*)d_in[9];
  const float* Wu  = (const float*)d_in[10];
  const float* Wd  = (const float*)d_in[11];
  float* out = (float*)d_out;
  char* ws = (char*)d_ws;

  // workspace layout (126.1 MB total, with lifetime-based aliasing)
  unsigned short* tk_bf  = (unsigned short*)(ws + 0);
  unsigned short* tv_bf  = (unsigned short*)(ws + 8388608);
  unsigned short* k_bf   = (unsigned short*)(ws + 16777216);
  unsigned short* v_bf   = (unsigned short*)(ws + 25165824);
  unsigned short* g_bf   = (unsigned short*)(ws + 0);         // aliases tk/tv/k/v (dead)
  unsigned short* q_bf   = (unsigned short*)(ws + 33554432);
  unsigned short* ctx_bf = (unsigned short*)(ws + 50331648);
  unsigned short* u_bf   = (unsigned short*)(ws + 33554432);  // aliases q/ctx (dead)
  unsigned short* wq_bf  = (unsigned short*)(ws + 67108864);
  unsigned short* wk_bf  = (unsigned short*)(ws + 71303168);
  unsigned short* wv_bf  = (unsigned short*)(ws + 71434240);
  unsigned short* wo_bf  = (unsigned short*)(ws + 71565312);
  unsigned short* wg_bf  = (unsigned short*)(ws + 75759616);
  unsigned short* wu_bf  = (unsigned short*)(ws + 84148224);
  unsigned short* wd_bf  = (unsigned short*)(ws + 92536832);
  unsigned short* h_bf   = (unsigned short*)(ws + 100925440);
  float*          x2     = (float*)(ws + 109314048);

  dim3 blk(256);
  auto cvt = [&](const float* src, unsigned short* dst, int n) {
    convert_f32_bf16<<<dim3(n / 1024), blk, 0, stream>>>(src, dst, n / 4);
  };
  cvt(Wq, wq_bf, 2097152);
  cvt(Wk, wk_bf, 65536);
  cvt(Wv, wv_bf, 65536);
  cvt(Wo, wo_bf, 2097152);
  cvt(Wg, wg_bf, 4194304);
  cvt(Wu, wu_bf, 4194304);
  cvt(Wd, wd_bf, 4194304);
  cvt(tk, tk_bf, 4194304);
  cvt(tv, tv_bf, 4194304);

  rmsnorm_kernel<<<dim3(4096), blk, 0, stream>>>(x, ln1, h_bf);
  gemm_nt<0, 1><<<dim3(16, 32), blk, 0, stream>>>(h_bf, wq_bf, nullptr, q_bf, 4096, 2048, 1024);
  rope_kernel<<<dim3(16384), blk, 0, stream>>>(q_bf);
  gemm_nt<0, 1><<<dim3(2, 128), blk, 0, stream>>>(tk_bf, wk_bf, nullptr, k_bf, 16384, 256, 256);
  gemm_nt<0, 1><<<dim3(2, 128), blk, 0, stream>>>(tv_bf, wv_bf, nullptr, v_bf, 16384, 256, 256);
  attn_kernel<<<dim3(4, 8, 8), dim3(512), 0, stream>>>(q_bf, k_bf, v_bf, ctx_bf);
  gemm_nt<1, 0><<<dim3(8, 32), blk, 0, stream>>>(ctx_bf, wo_bf, x, x2, 4096, 1024, 2048);
  rmsnorm_kernel<<<dim3(4096), blk, 0, stream>>>(x2, ln2, h_bf);
  gemm_nt<0, 1><<<dim3(32, 32), blk, 0, stream>>>(h_bf, wg_bf, nullptr, g_bf, 4096, 4096, 1024);
  gemm_nt<0, 1><<<dim3(32, 32), blk, 0, stream>>>(h_bf, wu_bf, nullptr, u_bf, 4096, 4096, 1024);
  act_kernel<<<dim3(8192), blk, 0, stream>>>(g_bf, u_bf, g_bf, 2097152);
  gemm_nt<1, 0><<<dim3(8, 32), blk, 0, stream>>>(g_bf, wd_bf, x2, out, 4096, 1024, 4096);
}